// Round 6
// baseline (246.699 us; speedup 1.0000x reference)
//
#include <hip/hip_runtime.h>

#define NN 50000
#define NE 800000
#define DK 128            // feature dim into layers 0/1
#define NN_PAD 50048      // multiple of 128 for GEMM row blocks

// window-ordered dense adjacency lists
#define SW 7              // src windows (src >> 13)
#define SUBCAP 20         // per-window cap (never hit at mean deg 16/7)
#define CAP2 64           // total per-node cap (never hit at mean deg 16)

// two-phase edge partition: bucket = dst >> 7 (128 nodes/bucket)
#define NPB 128
#define NBKT 391          // ceil(50000/128)
#define BKTCAP 4096       // avg 2048/bucket, Poisson std ~45 -> hugely safe

#define GRID_DUAL 391     // NN_PAD/128 — layer-1 GEMM (full-N, P2 epilogue)
#define GRID_HALF 782     // layer-0 GEMM: 128 rows x 64-col N-half per block
#define GRID_FIN  782     // final GEMM: 64-row tiles

// aggregate: one node per WAVE (R6) — removes the max-of-4-degree divergence
// waste of the old one-node-per-16-lane-group form. 2048 blocks: ~resident
// capacity + queued reservoir for block-grain work-conservation.
// MUST stay a separate wide-grid kernel (R2 lesson: fusing into the GEMM grid
// dropped gather occupancy 24->6 waves/CU, fetch 15->80MB).
// W must stay LDS-staged per block in GEMMs (R4 lesson).
#define AGG_BLOCKS 2048

typedef __attribute__((ext_vector_type(8))) short bf16x8;
typedef __attribute__((ext_vector_type(4))) float f32x4;
typedef __attribute__((ext_vector_type(2))) int   i32x2;
typedef __attribute__((ext_vector_type(4))) int   i32x4;
typedef __attribute__((ext_vector_type(4))) unsigned u32x4;
typedef __attribute__((ext_vector_type(8))) unsigned short u16x8;

__device__ inline unsigned short f2bf(float f) {
    unsigned u = __builtin_bit_cast(unsigned, f);
    u = (u + 0x7FFFu + ((u >> 16) & 1u)) >> 16;
    return (unsigned short)u;
}
__device__ inline float bfhi2f(unsigned u) {
    return __builtin_bit_cast(float, u & 0xFFFF0000u);
}
__device__ inline float bflo2f(unsigned u) {
    return __builtin_bit_cast(float, u << 16);
}
__device__ inline int clampn(int v) {           // ushort ids >= 0 already
    return v >= NN ? NN - 1 : v;
}
__device__ inline void acc16(float* acc, u32x4 v) {
    acc[0] += bflo2f(v.x); acc[1] += bfhi2f(v.x);
    acc[2] += bflo2f(v.y); acc[3] += bfhi2f(v.y);
    acc[4] += bflo2f(v.z); acc[5] += bfhi2f(v.z);
    acc[6] += bflo2f(v.w); acc[7] += bfhi2f(v.w);
}

// ---------------------------------------------------------------- adjacency build

// Phase 1: partition edges into dst-buckets. All global writes are
// per-bucket streams (runs of consecutive u32s), keeping the 6.4MB
// bucket buffer L2/L3-resident — no random 64B-line HBM writebacks.
__global__ __launch_bounds__(256) void partition_edges(const int* __restrict__ src,
                                                       const int* __restrict__ dst,
                                                       int* __restrict__ gcount,
                                                       unsigned* __restrict__ bucketbuf) {
    __shared__ int hist[NBKT];
    __shared__ int cur[NBKT];
    __shared__ int base[NBKT];
    int tid = threadIdx.x;
    for (int i = tid; i < NBKT; i += 256) { hist[i] = 0; cur[i] = 0; }
    __syncthreads();

    unsigned rec[8];
    int bkt[8];
    int e0 = (blockIdx.x * 256 + tid) * 8;       // NE % 8 == 0
    bool valid = e0 < NE;
    if (valid) {
        i32x4 sa = __builtin_nontemporal_load((const i32x4*)(src + e0));
        i32x4 sb = __builtin_nontemporal_load((const i32x4*)(src + e0 + 4));
        i32x4 da = __builtin_nontemporal_load((const i32x4*)(dst + e0));
        i32x4 db = __builtin_nontemporal_load((const i32x4*)(dst + e0 + 4));
        int ss[8] = {sa.x, sa.y, sa.z, sa.w, sb.x, sb.y, sb.z, sb.w};
        int dd[8] = {da.x, da.y, da.z, da.w, db.x, db.y, db.z, db.w};
        #pragma unroll
        for (int k = 0; k < 8; ++k) {
            bkt[k] = dd[k] >> 7;
            rec[k] = (unsigned)ss[k] | ((unsigned)(dd[k] & 127) << 16);
            atomicAdd(&hist[bkt[k]], 1);
        }
    }
    __syncthreads();
    for (int i = tid; i < NBKT; i += 256)
        base[i] = atomicAdd(&gcount[i], hist[i]);
    __syncthreads();
    if (valid) {
        #pragma unroll
        for (int k = 0; k < 8; ++k) {
            int pos = base[bkt[k]] + atomicAdd(&cur[bkt[k]], 1);
            if (pos < BKTCAP)
                bucketbuf[(size_t)bkt[k] * BKTCAP + pos] = rec[k];
        }
    }
}

// Phase 2: one block per bucket. Windowed histogram + slotting entirely in
// LDS; dense window-ordered eidx2 rows + deg written out coalesced.
__global__ __launch_bounds__(256) void build_lists(const int* __restrict__ gcount,
                                                   const unsigned* __restrict__ bucketbuf,
                                                   unsigned short* __restrict__ eidx2,
                                                   int* __restrict__ deg) {
    __shared__ unsigned short list[NPB * CAP2];   // 16 KB
    __shared__ int cnt[NPB * 8];                  // 4 KB
    __shared__ int cur[NPB * 8];                  // 4 KB
    __shared__ int off_[NPB * 8];                 // 4 KB
    int b = blockIdx.x, tid = threadIdx.x;
    int n0 = b << 7;
    int cntE = gcount[b];
    if (cntE > BKTCAP) cntE = BKTCAP;

    for (int i = tid; i < NPB * 8; i += 256) { cnt[i] = 0; cur[i] = 0; }
    u32x4* l4 = (u32x4*)list;
    for (int i = tid; i < NPB * CAP2 / 8; i += 256)
        l4[i] = (u32x4){0u, 0u, 0u, 0u};
    __syncthreads();

    const unsigned* bb = bucketbuf + (size_t)b * BKTCAP;
    for (int i = tid; i < cntE; i += 256) {
        unsigned r = bb[i];
        int nl = r >> 16;
        int w  = (r & 0xFFFFu) >> 13;
        atomicAdd(&cnt[nl * 8 + w], 1);
    }
    __syncthreads();

    if (tid < NPB) {
        int run = 0, dt = 0;
        #pragma unroll
        for (int w = 0; w < SW; ++w) {
            int c = cnt[tid * 8 + w];
            dt += c;
            off_[tid * 8 + w] = run;
            run += (c < SUBCAP) ? c : SUBCAP;
        }
        if (n0 + tid < NN) deg[n0 + tid] = dt;    // uncapped true degree
    }
    __syncthreads();

    for (int i = tid; i < cntE; i += 256) {
        unsigned r = bb[i];
        int s  = (int)(r & 0xFFFFu);
        int nl = r >> 16;
        int w  = s >> 13;
        int slot = atomicAdd(&cur[nl * 8 + w], 1);
        int pos  = off_[nl * 8 + w] + slot;
        if (slot < SUBCAP && pos < CAP2)
            list[nl * CAP2 + pos] = (unsigned short)s;
    }
    __syncthreads();

    int nvalid = NN - n0;
    if (nvalid > NPB) nvalid = NPB;
    u32x4* out4 = (u32x4*)(eidx2 + (size_t)n0 * CAP2);
    for (int i = tid; i < nvalid * (CAP2 / 8); i += 256)
        __builtin_nontemporal_store(l4[i], out4 + i);
}

// ---------------------------------------------------------------- prep (fused setup)
// blocks [0,3128): x -> bf16 (+ zero NN..NN_PAD pad rows)
// next 32: dual W packs (16 for layer0, 16 for layer1)
// next 8:  single W packs (4 Wl2, 4 Wr2)
// last 1:  zero gcount
__global__ __launch_bounds__(256) void prep(const float* __restrict__ x,
                                            unsigned short* __restrict__ xb,
                                            const float* __restrict__ Wl0,
                                            const float* __restrict__ Wr0,
                                            unsigned short* __restrict__ Wp0,
                                            const float* __restrict__ Wl1,
                                            const float* __restrict__ Wr1,
                                            unsigned short* __restrict__ Wp1,
                                            const float* __restrict__ Wl2,
                                            unsigned short* __restrict__ Wp2l,
                                            const float* __restrict__ Wr2,
                                            unsigned short* __restrict__ Wp2r,
                                            int* __restrict__ gcount) {
    int b = blockIdx.x;
    if (b < NN_PAD * DK / 8 / 256) {                       // 3128 convert blocks
        long long i = ((long long)b * 256 + threadIdx.x) * 8;
        if (i < (long long)NN * DK) {
            f32x4 a = __builtin_nontemporal_load((const f32x4*)(x + i));
            f32x4 c = __builtin_nontemporal_load((const f32x4*)(x + i + 4));
            union { unsigned short us[8]; u32x4 u4; } o;
            o.us[0] = f2bf(a.x); o.us[1] = f2bf(a.y); o.us[2] = f2bf(a.z); o.us[3] = f2bf(a.w);
            o.us[4] = f2bf(c.x); o.us[5] = f2bf(c.y); o.us[6] = f2bf(c.z); o.us[7] = f2bf(c.w);
            *(u32x4*)(xb + i) = o.u4;
        } else {
            *(u32x4*)(xb + i) = (u32x4){0u, 0u, 0u, 0u};   // pad rows -> 0
        }
        return;
    }
    b -= NN_PAD * DK / 8 / 256;
    if (b < 32) {                                          // dual 256x128 packs
        const float* Wl = (b < 16) ? Wl0 : Wl1;
        const float* Wr = (b < 16) ? Wr0 : Wr1;
        unsigned short* Wp = (b < 16) ? Wp0 : Wp1;
        int tid = (b & 15) * 256 + threadIdx.x;            // 0..4095
        int l  = tid & 63;
        int ks = (tid >> 6) & 7;
        int nt = tid >> 9;
        int n  = nt * 16 + (l & 15);
        int kb = ks * 32 + (l >> 4) * 8;
        union { unsigned short us[8]; u32x4 u4; } o;
        #pragma unroll
        for (int j = 0; j < 8; ++j) {
            int k = kb + j;
            float w = (k < 128) ? Wl[k * 128 + n] : Wr[(k - 128) * 128 + n];
            o.us[j] = f2bf(w);
        }
        *(u32x4*)(Wp + (size_t)tid * 8) = o.u4;
        return;
    }
    b -= 32;
    if (b < 8) {                                           // single 128x64 packs
        const float* W = (b < 4) ? Wl2 : Wr2;
        unsigned short* Wp = (b < 4) ? Wp2l : Wp2r;
        int tid = (b & 3) * 256 + threadIdx.x;             // 0..1023
        int l  = tid & 63;
        int ks = (tid >> 6) & 3;
        int nt = tid >> 8;
        int n  = nt * 16 + (l & 15);
        int kb = ks * 32 + (l >> 4) * 8;
        union { unsigned short us[8]; u32x4 u4; } o;
        #pragma unroll
        for (int j = 0; j < 8; ++j) o.us[j] = f2bf(W[(kb + j) * 64 + n]);
        *(u32x4*)(Wp + (size_t)tid * 8) = o.u4;
        return;
    }
    for (int i = threadIdx.x; i < NBKT; i += 256) gcount[i] = 0;
}

// ---------------------------------------------------------------- aggregation (bf16)
// R6: ONE NODE PER WAVE. Lane = (q, l): q = edge-subgroup, l = dim-chunk (16B).
// All 64 lanes work the same node -> trip count depends only on this node's
// degree (no max-of-4-groups divergence waste); each wave sweeps ~6 nodes
// sequentially (CLT-smoothed makespan). Requests identical to the old form
// (masked lanes issue nothing); only issue slots / balance change.
// S = 16B-chunks per feature row (16 -> 128 dims, 8 -> 64 dims).
template <int S>
__global__ __launch_bounds__(256) void aggregate(const unsigned short* __restrict__ h,
                                                 const unsigned short* __restrict__ eidx2,
                                                 const int* __restrict__ deg,
                                                 unsigned short* __restrict__ agg) {
    int lane = threadIdx.x & 63;
    int q = lane / S;                       // edge-subgroup: 0..3 (S=16) / 0..7 (S=8)
    int l = lane % S;                       // dim-chunk
    int wv = blockIdx.x * 4 + (threadIdx.x >> 6);
    const u32x4* h4 = (const u32x4*)h;

    for (int node = wv; node < NN; node += AGG_BLOCKS * 4) {
        int d   = deg[node];
        int cap = (d < CAP2) ? d : CAP2;
        const unsigned short* el = eidx2 + (size_t)node * CAP2;  // 128B row, zero-padded
        float acc[8] = {0.f, 0.f, 0.f, 0.f, 0.f, 0.f, 0.f, 0.f};
        int j = 0;
        if constexpr (S == 16) {
            // unmasked 32-edge chunks: 8 edges/lane, ILP 8 (heavy nodes)
            for (; j + 31 < cap; j += 32) {
                u16x8 i8 = *(const u16x8*)(el + j + q * 8);     // in-row: j+31 <= 63
                u32x4 v[8];
                #pragma unroll
                for (int t = 0; t < 8; ++t)
                    v[t] = h4[(size_t)clampn((int)i8[t]) * S + l];
                #pragma unroll
                for (int t = 0; t < 8; ++t) acc16(acc, v[t]);
            }
            // masked 16-edge chunks: 4 edges/lane, ILP 4 (modal d~16 path)
            for (; j < cap; j += 16) {
                ushort4 i4 = *(const ushort4*)(el + j + q * 4); // in-row: j+15 <= 63
                int idx[4] = {i4.x, i4.y, i4.z, i4.w};
                #pragma unroll
                for (int t = 0; t < 4; ++t) {
                    int e = j + q * 4 + t;
                    if (e < cap)
                        acc16(acc, h4[(size_t)clampn(idx[t]) * S + l]);
                }
            }
        } else {                            // S == 8: 8 edge-subgroups
            // masked 32-edge chunks: 4 edges/lane, ILP 4
            for (; j < cap; j += 32) {
                ushort4 i4 = *(const ushort4*)(el + j + q * 4); // in-row: j+31 <= 63
                int idx[4] = {i4.x, i4.y, i4.z, i4.w};
                #pragma unroll
                for (int t = 0; t < 4; ++t) {
                    int e = j + q * 4 + t;
                    if (e < cap)
                        acc16(acc, h4[(size_t)clampn(idx[t]) * S + l]);
                }
            }
        }
        // reduce across edge-subgroups (q spans lane bits >= log2(S))
        #pragma unroll
        for (int k = 0; k < 8; ++k) {
            if constexpr (S == 8) acc[k] += __shfl_xor(acc[k], 8);
            acc[k] += __shfl_xor(acc[k], 16);
            acc[k] += __shfl_xor(acc[k], 32);
        }
        if (lane < S) {
            float r = 1.0f / (float)(d > 0 ? d : 1);
            union { unsigned short us[8]; u32x4 u4; } o;
            #pragma unroll
            for (int k = 0; k < 8; ++k) o.us[k] = f2bf(acc[k] * r);
            __builtin_nontemporal_store(o.u4, (u32x4*)agg + (size_t)node * S + l);
        }
    }
}

// ---------------------------------------------------------------- MFMA GEMMs

// layer 0: out = relu( agg@Wl + h@Wr + b ), split-N: each block does all 128
// rows x one 64-col N-half, staging the contiguous 32KB half of the dual pack.
// 5 blocks/CU LDS-limited -> all 782 blocks co-resident (no 2-round makespan).
__global__ __launch_bounds__(256) void gemm_half(const unsigned short* __restrict__ agg,
                                                 const unsigned short* __restrict__ h,
                                                 const unsigned short* __restrict__ Wpack,
                                                 const float* __restrict__ bias,
                                                 unsigned short* __restrict__ out) {
    __shared__ unsigned short Wlds[128 * 128];    // 32 KB
    int tid = threadIdx.x;
    int nh = blockIdx.x & 1;
    int rb = blockIdx.x >> 1;
    {
        const u32x4* wg = (const u32x4*)Wpack + nh * 2048;
        u32x4* wl = (u32x4*)Wlds;
        #pragma unroll
        for (int i = tid; i < 2048; i += 256) wl[i] = wg[i];
    }
    __syncthreads();

    int wave = tid >> 6, lane = tid & 63;
    int m = lane & 15, quad = lane >> 4;
    int r0 = wave * 16;                           // second tile at r0 + 64
    int row0 = rb * 128 + r0;

    const unsigned short* arow = agg + (size_t)(row0 + m) * 128 + quad * 8;
    const unsigned short* hrow = h   + (size_t)(row0 + m) * 128 + quad * 8;

    f32x4 acc0[4] = {};
    f32x4 acc1[4] = {};
    #pragma unroll
    for (int ks = 0; ks < 8; ++ks) {
        const unsigned short* s = (ks < 4) ? (arow + ks * 32) : (hrow + (ks - 4) * 32);
        bf16x8 a0 = *(const bf16x8*)s;
        bf16x8 a1 = *(const bf16x8*)(s + 64 * 128);
        #pragma unroll
        for (int nt = 0; nt < 4; ++nt) {
            bf16x8 b = *(const bf16x8*)&Wlds[((nt * 8 + ks) * 64 + lane) * 8];
            acc0[nt] = __builtin_amdgcn_mfma_f32_16x16x32_bf16(a0, b, acc0[nt], 0, 0, 0);
            acc1[nt] = __builtin_amdgcn_mfma_f32_16x16x32_bf16(a1, b, acc1[nt], 0, 0, 0);
        }
    }

    #pragma unroll
    for (int t = 0; t < 2; ++t) {
        #pragma unroll
        for (int nt = 0; nt < 4; ++nt) {
            int n = nh * 64 + nt * 16 + m;
            float bv = bias[n];
            #pragma unroll
            for (int r = 0; r < 4; ++r) {
                int row = row0 + t * 64 + quad * 4 + r;   // < NN_PAD; pad rows ok
                float v = fmaxf((t == 0 ? acc0[nt][r] : acc1[nt][r]) + bv, 0.f);
                out[(size_t)row * 128 + n] = f2bf(v);
            }
        }
    }
}

// layer 1: out = relu( agg@Wl + h@Wr + b ), full-N 128-row blocks + fused
// P2 = h2@Wl2 epilogue (needs all 128 h2 cols -> can't split N). Reuses the
// dead 64KB Wlds as the h2 staging tile (barrier-guarded; each wave reads back
// only the rows it wrote -> wave-internal lgkmcnt ordering suffices).
__global__ __launch_bounds__(256) void gemm_dual(const unsigned short* __restrict__ agg,
                                                 const unsigned short* __restrict__ h,
                                                 const unsigned short* __restrict__ Wpack,
                                                 const float* __restrict__ bias,
                                                 unsigned short* __restrict__ out,
                                                 const unsigned short* __restrict__ Wp2,
                                                 unsigned short* __restrict__ P2) {
    __shared__ unsigned short Wlds[128 * 256];    // 64 KB
    int tid = threadIdx.x;
    {
        const u32x4* wg = (const u32x4*)Wpack;
        u32x4* wl = (u32x4*)Wlds;
        #pragma unroll
        for (int i = tid; i < 128 * 32; i += 256) wl[i] = wg[i];
    }
    __syncthreads();

    int wave = tid >> 6, lane = tid & 63;
    int m = lane & 15, quad = lane >> 4;
    int r0 = wave * 16;                           // second tile at r0 + 64
    int row0 = blockIdx.x * 128 + r0;

    const unsigned short* arow = agg + (size_t)(row0 + m) * 128 + quad * 8;
    const unsigned short* hrow = h   + (size_t)(row0 + m) * 128 + quad * 8;

    f32x4 acc0[8] = {};
    f32x4 acc1[8] = {};
    #pragma unroll
    for (int ks = 0; ks < 8; ++ks) {
        const unsigned short* s = (ks < 4) ? (arow + ks * 32) : (hrow + (ks - 4) * 32);
        bf16x8 a0 = *(const bf16x8*)s;
        bf16x8 a1 = *(const bf16x8*)(s + 64 * 128);
        #pragma unroll
        for (int nt = 0; nt < 8; ++nt) {
            bf16x8 b = *(const bf16x8*)&Wlds[((nt * 8 + ks) * 64 + lane) * 8];
            acc0[nt] = __builtin_amdgcn_mfma_f32_16x16x32_bf16(a0, b, acc0[nt], 0, 0, 0);
            acc1[nt] = __builtin_amdgcn_mfma_f32_16x16x32_bf16(a1, b, acc1[nt], 0, 0, 0);
        }
    }

    #pragma unroll
    for (int t = 0; t < 2; ++t) {
        #pragma unroll
        for (int nt = 0; nt < 8; ++nt) {
            int n = nt * 16 + m;
            float bv = bias[n];
            #pragma unroll
            for (int r = 0; r < 4; ++r) {
                int row = row0 + t * 64 + quad * 4 + r;   // < NN_PAD; pad rows ok
                float v = fmaxf((t == 0 ? acc0[nt][r] : acc1[nt][r]) + bv, 0.f);
                out[(size_t)row * 128 + n] = f2bf(v);
            }
        }
    }

    {
        constexpr int RS = 136;                   // padded row stride (shorts)
        __syncthreads();                          // Wlds reads done by all waves
        #pragma unroll
        for (int t = 0; t < 2; ++t) {
            #pragma unroll
            for (int nt = 0; nt < 8; ++nt) {
                int n = nt * 16 + m;
                float bv = bias[n];
                #pragma unroll
                for (int r = 0; r < 4; ++r) {
                    int rl = t * 64 + r0 + quad * 4 + r;
                    float v = fmaxf((t == 0 ? acc0[nt][r] : acc1[nt][r]) + bv, 0.f);
                    Wlds[rl * RS + n] = f2bf(v);
                }
            }
        }
        f32x4 p0[4] = {};
        f32x4 p1[4] = {};
        #pragma unroll
        for (int ks = 0; ks < 4; ++ks) {
            bf16x8 a0 = *(const bf16x8*)&Wlds[(r0 + m) * RS + ks * 32 + quad * 8];
            bf16x8 a1 = *(const bf16x8*)&Wlds[(64 + r0 + m) * RS + ks * 32 + quad * 8];
            #pragma unroll
            for (int nt = 0; nt < 4; ++nt) {
                bf16x8 bfr = *(const bf16x8*)&Wp2[((size_t)(nt * 4 + ks) * 64 + lane) * 8];
                p0[nt] = __builtin_amdgcn_mfma_f32_16x16x32_bf16(a0, bfr, p0[nt], 0, 0, 0);
                p1[nt] = __builtin_amdgcn_mfma_f32_16x16x32_bf16(a1, bfr, p1[nt], 0, 0, 0);
            }
        }
        #pragma unroll
        for (int t = 0; t < 2; ++t) {
            #pragma unroll
            for (int nt = 0; nt < 4; ++nt) {
                int n = nt * 16 + m;
                #pragma unroll
                for (int r = 0; r < 4; ++r) {
                    int rl = t * 64 + r0 + quad * 4 + r;
                    P2[(size_t)(blockIdx.x * 128 + rl) * 64 + n] =
                        f2bf(t == 0 ? p0[nt][r] : p1[nt][r]);
                }
            }
        }
    }
}

// out = h @ Wr2 + aggP + bias (K=128, N=64), fp32 out — layer-2 final.
// 64-row tiles (782 blocks), 16KB W stage -> fully co-resident & balanced.
__global__ __launch_bounds__(256) void gemm_final(const unsigned short* __restrict__ h,
                                                  const unsigned short* __restrict__ Wpack,
                                                  const float* __restrict__ bias,
                                                  const unsigned short* __restrict__ aggP,
                                                  float* __restrict__ outp) {
    __shared__ unsigned short Wlds[64 * 128];     // 16 KB
    int tid = threadIdx.x;
    {
        const u32x4* wg = (const u32x4*)Wpack;
        u32x4* wl = (u32x4*)Wlds;
        #pragma unroll
        for (int i = tid; i < 1024; i += 256) wl[i] = wg[i];
    }
    __syncthreads();

    int wave = tid >> 6, lane = tid & 63;
    int m = lane & 15, quad = lane >> 4;
    int row0 = blockIdx.x * 64 + wave * 16;

    const unsigned short* hrow = h + (size_t)(row0 + m) * 128 + quad * 8;

    f32x4 acc0[4] = {};
    #pragma unroll
    for (int ks = 0; ks < 4; ++ks) {
        bf16x8 a0 = *(const bf16x8*)(hrow + ks * 32);
        #pragma unroll
        for (int nt = 0; nt < 4; ++nt) {
            bf16x8 b = *(const bf16x8*)&Wlds[((nt * 4 + ks) * 64 + lane) * 8];
            acc0[nt] = __builtin_amdgcn_mfma_f32_16x16x32_bf16(a0, b, acc0[nt], 0, 0, 0);
        }
    }

    #pragma unroll
    for (int nt = 0; nt < 4; ++nt) {
        int n = nt * 16 + m;
        float bv = bias[n];
        #pragma unroll
        for (int r = 0; r < 4; ++r) {
            int row = row0 + quad * 4 + r;
            if (row < NN) {
                float av = bflo2f((unsigned)aggP[(size_t)row * 64 + n]);
                outp[(size_t)row * 64 + n] = acc0[nt][r] + bv + av;
            }
        }
    }
}

// ---------------------------------------------------------------- launch

static inline size_t align256(size_t x) { return (x + 255) & ~(size_t)255; }

extern "C" void kernel_launch(void* const* d_in, const int* in_sizes, int n_in,
                              void* d_out, int out_size, void* d_ws, size_t ws_size,
                              hipStream_t stream) {
    const float* x    = (const float*)d_in[0];
    const int*   ei   = (const int*)d_in[1];
    const int*   esrc = ei;
    const int*   edst = ei + NE;
    const float* Wl0 = (const float*)d_in[2];
    const float* bl0 = (const float*)d_in[3];
    const float* Wr0 = (const float*)d_in[4];
    const float* Wl1 = (const float*)d_in[5];
    const float* bl1 = (const float*)d_in[6];
    const float* Wr1 = (const float*)d_in[7];
    const float* Wl2 = (const float*)d_in[8];
    const float* bl2 = (const float*)d_in[9];
    const float* Wr2 = (const float*)d_in[10];

    char* ws = (char*)d_ws;
    size_t off = 0;
    int* gcount = (int*)(ws + off);             off = align256(off + (size_t)NBKT * 4);
    unsigned* bucketbuf = (unsigned*)(ws + off);
    off = align256(off + (size_t)NBKT * BKTCAP * 4);
    unsigned short* eidx2 = (unsigned short*)(ws + off);
    off = align256(off + (size_t)NN * CAP2 * 2);
    int* deg = (int*)(ws + off);                off = align256(off + (size_t)NN * 4);
    unsigned short* xb   = (unsigned short*)(ws + off); off = align256(off + (size_t)NN_PAD * DK * 2);
    unsigned short* bAgg = (unsigned short*)(ws + off); off = align256(off + (size_t)NN_PAD * DK * 2);
    unsigned short* bH   = (unsigned short*)(ws + off); off = align256(off + (size_t)NN_PAD * DK * 2);
    unsigned short* P2   = (unsigned short*)(ws + off); off = align256(off + (size_t)NN_PAD * 64 * 2);
    unsigned short* aggP = (unsigned short*)(ws + off); off = align256(off + (size_t)NN_PAD * 64 * 2);
    unsigned short* Wp0  = (unsigned short*)(ws + off); off = align256(off + (size_t)256 * 128 * 2);
    unsigned short* Wp1  = (unsigned short*)(ws + off); off = align256(off + (size_t)256 * 128 * 2);
    unsigned short* Wp2l = (unsigned short*)(ws + off); off = align256(off + (size_t)128 * 64 * 2);
    unsigned short* Wp2r = (unsigned short*)(ws + off); off = align256(off + (size_t)128 * 64 * 2);

    // ---- setup: convert + packs + gcount zero, then adjacency build ----
    prep<<<NN_PAD * DK / 8 / 256 + 32 + 8 + 1, 256, 0, stream>>>(
        x, xb, Wl0, Wr0, Wp0, Wl1, Wr1, Wp1, Wl2, Wp2l, Wr2, Wp2r, gcount);
    partition_edges<<<(NE / 8 + 255) / 256, 256, 0, stream>>>(esrc, edst, gcount, bucketbuf);
    build_lists<<<NBKT, 256, 0, stream>>>(gcount, bucketbuf, eidx2, deg);

    // ---- layer 0: xb -> bH (relu), split-N GEMM ----
    aggregate<16><<<AGG_BLOCKS, 256, 0, stream>>>(xb, eidx2, deg, bAgg);
    gemm_half<<<GRID_HALF, 256, 0, stream>>>(bAgg, xb, Wp0, bl0, bH);

    // ---- layer 1 (+ fused P2 = h2@Wl2): bH -> xb, P2 ----
    aggregate<16><<<AGG_BLOCKS, 256, 0, stream>>>(bH, eidx2, deg, bAgg);
    gemm_dual<<<GRID_DUAL, 256, 0, stream>>>(bAgg, bH, Wp1, bl1, xb, Wp2l, P2);

    // ---- layer 2: out = xb@Wr2 + agg(P2) + bias ----
    aggregate<8><<<AGG_BLOCKS, 256, 0, stream>>>(P2, eidx2, deg, aggP);
    gemm_final<<<GRID_FIN, 256, 0, stream>>>(xb, Wp2r, bl2, aggP, (float*)d_out);
}

// Round 7
// 241.662 us; speedup vs baseline: 1.0208x; 1.0208x over previous
//
#include <hip/hip_runtime.h>

#define NN 50000
#define NE 800000
#define DK 128            // feature dim into layers 0/1
#define NN_PAD 50048      // multiple of 128 for GEMM row blocks

// window-ordered dense adjacency lists
#define SW 7              // src windows (src >> 13)
#define SUBCAP 20         // per-window cap (never hit at mean deg 16/7)
#define CAP2 64           // total per-node cap (never hit at mean deg 16)

// two-phase edge partition: bucket = dst >> 7 (128 nodes/bucket)
#define NPB 128
#define NBKT 391          // ceil(50000/128)
#define BKTCAP 4096       // avg 2048/bucket, Poisson std ~45 -> hugely safe

#define GRID_DUAL 391     // NN_PAD/128 — layer-1 GEMM (full-N, P2 epilogue)
#define GRID_HALF 782     // layer-0 GEMM: 128 rows x 64-col N-half per block
#define GRID_FIN  782     // final GEMM: 64-row tiles

// aggregate: one node per 16-lane group (R5 form — R6's one-node-per-wave cut
// per-lane gather ILP 8->4 and cost +5us/aggregate). R7: deepen to 16
// outstanding gathers/lane (modal d~16 = one issue burst, one latency drain).
// MUST stay a separate wide-grid kernel (R2 lesson: fusing into the GEMM grid
// dropped gather occupancy 24->6 waves/CU, fetch 15->80MB).
// W must stay LDS-staged per block in GEMMs (R4 lesson).
#define AGG_BLOCKS 1568

typedef __attribute__((ext_vector_type(8))) short bf16x8;
typedef __attribute__((ext_vector_type(4))) float f32x4;
typedef __attribute__((ext_vector_type(2))) int   i32x2;
typedef __attribute__((ext_vector_type(4))) int   i32x4;
typedef __attribute__((ext_vector_type(4))) unsigned u32x4;
typedef __attribute__((ext_vector_type(8))) unsigned short u16x8;

__device__ inline unsigned short f2bf(float f) {
    unsigned u = __builtin_bit_cast(unsigned, f);
    u = (u + 0x7FFFu + ((u >> 16) & 1u)) >> 16;
    return (unsigned short)u;
}
__device__ inline float bfhi2f(unsigned u) {
    return __builtin_bit_cast(float, u & 0xFFFF0000u);
}
__device__ inline float bflo2f(unsigned u) {
    return __builtin_bit_cast(float, u << 16);
}
__device__ inline int clampn(int v) {           // ushort ids >= 0 already
    return v >= NN ? NN - 1 : v;
}
__device__ inline void acc16(float* acc, u32x4 v) {
    acc[0] += bflo2f(v.x); acc[1] += bfhi2f(v.x);
    acc[2] += bflo2f(v.y); acc[3] += bfhi2f(v.y);
    acc[4] += bflo2f(v.z); acc[5] += bfhi2f(v.z);
    acc[6] += bflo2f(v.w); acc[7] += bfhi2f(v.w);
}

// ---------------------------------------------------------------- adjacency build

// Phase 1: partition edges into dst-buckets. All global writes are
// per-bucket streams (runs of consecutive u32s), keeping the 6.4MB
// bucket buffer L2/L3-resident — no random 64B-line HBM writebacks.
__global__ __launch_bounds__(256) void partition_edges(const int* __restrict__ src,
                                                       const int* __restrict__ dst,
                                                       int* __restrict__ gcount,
                                                       unsigned* __restrict__ bucketbuf) {
    __shared__ int hist[NBKT];
    __shared__ int cur[NBKT];
    __shared__ int base[NBKT];
    int tid = threadIdx.x;
    for (int i = tid; i < NBKT; i += 256) { hist[i] = 0; cur[i] = 0; }
    __syncthreads();

    unsigned rec[8];
    int bkt[8];
    int e0 = (blockIdx.x * 256 + tid) * 8;       // NE % 8 == 0
    bool valid = e0 < NE;
    if (valid) {
        i32x4 sa = __builtin_nontemporal_load((const i32x4*)(src + e0));
        i32x4 sb = __builtin_nontemporal_load((const i32x4*)(src + e0 + 4));
        i32x4 da = __builtin_nontemporal_load((const i32x4*)(dst + e0));
        i32x4 db = __builtin_nontemporal_load((const i32x4*)(dst + e0 + 4));
        int ss[8] = {sa.x, sa.y, sa.z, sa.w, sb.x, sb.y, sb.z, sb.w};
        int dd[8] = {da.x, da.y, da.z, da.w, db.x, db.y, db.z, db.w};
        #pragma unroll
        for (int k = 0; k < 8; ++k) {
            bkt[k] = dd[k] >> 7;
            rec[k] = (unsigned)ss[k] | ((unsigned)(dd[k] & 127) << 16);
            atomicAdd(&hist[bkt[k]], 1);
        }
    }
    __syncthreads();
    for (int i = tid; i < NBKT; i += 256)
        base[i] = atomicAdd(&gcount[i], hist[i]);
    __syncthreads();
    if (valid) {
        #pragma unroll
        for (int k = 0; k < 8; ++k) {
            int pos = base[bkt[k]] + atomicAdd(&cur[bkt[k]], 1);
            if (pos < BKTCAP)
                bucketbuf[(size_t)bkt[k] * BKTCAP + pos] = rec[k];
        }
    }
}

// Phase 2: one block per bucket. Windowed histogram + slotting entirely in
// LDS; dense window-ordered eidx2 rows + deg written out coalesced.
__global__ __launch_bounds__(256) void build_lists(const int* __restrict__ gcount,
                                                   const unsigned* __restrict__ bucketbuf,
                                                   unsigned short* __restrict__ eidx2,
                                                   int* __restrict__ deg) {
    __shared__ unsigned short list[NPB * CAP2];   // 16 KB
    __shared__ int cnt[NPB * 8];                  // 4 KB
    __shared__ int cur[NPB * 8];                  // 4 KB
    __shared__ int off_[NPB * 8];                 // 4 KB
    int b = blockIdx.x, tid = threadIdx.x;
    int n0 = b << 7;
    int cntE = gcount[b];
    if (cntE > BKTCAP) cntE = BKTCAP;

    for (int i = tid; i < NPB * 8; i += 256) { cnt[i] = 0; cur[i] = 0; }
    u32x4* l4 = (u32x4*)list;
    for (int i = tid; i < NPB * CAP2 / 8; i += 256)
        l4[i] = (u32x4){0u, 0u, 0u, 0u};
    __syncthreads();

    const unsigned* bb = bucketbuf + (size_t)b * BKTCAP;
    for (int i = tid; i < cntE; i += 256) {
        unsigned r = bb[i];
        int nl = r >> 16;
        int w  = (r & 0xFFFFu) >> 13;
        atomicAdd(&cnt[nl * 8 + w], 1);
    }
    __syncthreads();

    if (tid < NPB) {
        int run = 0, dt = 0;
        #pragma unroll
        for (int w = 0; w < SW; ++w) {
            int c = cnt[tid * 8 + w];
            dt += c;
            off_[tid * 8 + w] = run;
            run += (c < SUBCAP) ? c : SUBCAP;
        }
        if (n0 + tid < NN) deg[n0 + tid] = dt;    // uncapped true degree
    }
    __syncthreads();

    for (int i = tid; i < cntE; i += 256) {
        unsigned r = bb[i];
        int s  = (int)(r & 0xFFFFu);
        int nl = r >> 16;
        int w  = s >> 13;
        int slot = atomicAdd(&cur[nl * 8 + w], 1);
        int pos  = off_[nl * 8 + w] + slot;
        if (slot < SUBCAP && pos < CAP2)
            list[nl * CAP2 + pos] = (unsigned short)s;
    }
    __syncthreads();

    int nvalid = NN - n0;
    if (nvalid > NPB) nvalid = NPB;
    u32x4* out4 = (u32x4*)(eidx2 + (size_t)n0 * CAP2);
    for (int i = tid; i < nvalid * (CAP2 / 8); i += 256)
        __builtin_nontemporal_store(l4[i], out4 + i);
}

// ---------------------------------------------------------------- prep (fused setup)
// blocks [0,3128): x -> bf16 (+ zero NN..NN_PAD pad rows)
// next 32: dual W packs (16 for layer0, 16 for layer1)
// next 8:  single W packs (4 Wl2, 4 Wr2)
// last 1:  zero gcount
__global__ __launch_bounds__(256) void prep(const float* __restrict__ x,
                                            unsigned short* __restrict__ xb,
                                            const float* __restrict__ Wl0,
                                            const float* __restrict__ Wr0,
                                            unsigned short* __restrict__ Wp0,
                                            const float* __restrict__ Wl1,
                                            const float* __restrict__ Wr1,
                                            unsigned short* __restrict__ Wp1,
                                            const float* __restrict__ Wl2,
                                            unsigned short* __restrict__ Wp2l,
                                            const float* __restrict__ Wr2,
                                            unsigned short* __restrict__ Wp2r,
                                            int* __restrict__ gcount) {
    int b = blockIdx.x;
    if (b < NN_PAD * DK / 8 / 256) {                       // 3128 convert blocks
        long long i = ((long long)b * 256 + threadIdx.x) * 8;
        if (i < (long long)NN * DK) {
            f32x4 a = __builtin_nontemporal_load((const f32x4*)(x + i));
            f32x4 c = __builtin_nontemporal_load((const f32x4*)(x + i + 4));
            union { unsigned short us[8]; u32x4 u4; } o;
            o.us[0] = f2bf(a.x); o.us[1] = f2bf(a.y); o.us[2] = f2bf(a.z); o.us[3] = f2bf(a.w);
            o.us[4] = f2bf(c.x); o.us[5] = f2bf(c.y); o.us[6] = f2bf(c.z); o.us[7] = f2bf(c.w);
            *(u32x4*)(xb + i) = o.u4;
        } else {
            *(u32x4*)(xb + i) = (u32x4){0u, 0u, 0u, 0u};   // pad rows -> 0
        }
        return;
    }
    b -= NN_PAD * DK / 8 / 256;
    if (b < 32) {                                          // dual 256x128 packs
        const float* Wl = (b < 16) ? Wl0 : Wl1;
        const float* Wr = (b < 16) ? Wr0 : Wr1;
        unsigned short* Wp = (b < 16) ? Wp0 : Wp1;
        int tid = (b & 15) * 256 + threadIdx.x;            // 0..4095
        int l  = tid & 63;
        int ks = (tid >> 6) & 7;
        int nt = tid >> 9;
        int n  = nt * 16 + (l & 15);
        int kb = ks * 32 + (l >> 4) * 8;
        union { unsigned short us[8]; u32x4 u4; } o;
        #pragma unroll
        for (int j = 0; j < 8; ++j) {
            int k = kb + j;
            float w = (k < 128) ? Wl[k * 128 + n] : Wr[(k - 128) * 128 + n];
            o.us[j] = f2bf(w);
        }
        *(u32x4*)(Wp + (size_t)tid * 8) = o.u4;
        return;
    }
    b -= 32;
    if (b < 8) {                                           // single 128x64 packs
        const float* W = (b < 4) ? Wl2 : Wr2;
        unsigned short* Wp = (b < 4) ? Wp2l : Wp2r;
        int tid = (b & 3) * 256 + threadIdx.x;             // 0..1023
        int l  = tid & 63;
        int ks = (tid >> 6) & 3;
        int nt = tid >> 8;
        int n  = nt * 16 + (l & 15);
        int kb = ks * 32 + (l >> 4) * 8;
        union { unsigned short us[8]; u32x4 u4; } o;
        #pragma unroll
        for (int j = 0; j < 8; ++j) o.us[j] = f2bf(W[(kb + j) * 64 + n]);
        *(u32x4*)(Wp + (size_t)tid * 8) = o.u4;
        return;
    }
    for (int i = threadIdx.x; i < NBKT; i += 256) gcount[i] = 0;
}

// ---------------------------------------------------------------- aggregation (bf16)
// R5 form (one node per S-lane group) + R7: 16-deep head loop — 16 outstanding
// gathers/lane so the modal d~16 node is one issue-burst + one latency drain
// (R5's 8-deep ran two serial drains; R6 proved the gather is ILP/latency-
// sensitive by regressing at depth 4). Tails 8/4/1 unchanged.
// S = 16B-chunks per feature row (16 -> 128 dims, 8 -> 64 dims).
template <int S>
__global__ __launch_bounds__(256) void aggregate(const unsigned short* __restrict__ h,
                                                 const unsigned short* __restrict__ eidx2,
                                                 const int* __restrict__ deg,
                                                 unsigned short* __restrict__ agg) {
    constexpr int NPB_ = 256 / S;         // nodes per block
    int g    = threadIdx.x / S;
    int lane = threadIdx.x % S;
    const u32x4* h4 = (const u32x4*)h;
    for (int base = 0; base < NN; base += AGG_BLOCKS * NPB_) {
        int node = base + blockIdx.x * NPB_ + g;
        if (node >= NN) continue;
        int d   = deg[node];
        int cap = (d < CAP2) ? d : CAP2;
        const unsigned short* el = eidx2 + (size_t)node * CAP2;  // 128B aligned
        float acc[8] = {0.f, 0.f, 0.f, 0.f, 0.f, 0.f, 0.f, 0.f};
        int j = 0;
        for (; j + 15 < cap; j += 16) {
            u16x8 i8a = *(const u16x8*)(el + j);     // 16B aligned (j%16==0)
            u16x8 i8b = *(const u16x8*)(el + j + 8);
            u32x4 v[16];
            #pragma unroll
            for (int q = 0; q < 8; ++q)
                v[q] = h4[(size_t)clampn((int)i8a[q]) * S + lane];
            #pragma unroll
            for (int q = 0; q < 8; ++q)
                v[8 + q] = h4[(size_t)clampn((int)i8b[q]) * S + lane];
            #pragma unroll
            for (int q = 0; q < 16; ++q) acc16(acc, v[q]);
        }
        for (; j + 7 < cap; j += 8) {
            u16x8 i8 = *(const u16x8*)(el + j);      // 16B aligned (j%8==0)
            u32x4 v[8];
            #pragma unroll
            for (int q = 0; q < 8; ++q)
                v[q] = h4[(size_t)clampn((int)i8[q]) * S + lane];
            #pragma unroll
            for (int q = 0; q < 8; ++q) acc16(acc, v[q]);
        }
        for (; j + 3 < cap; j += 4) {
            u32x4 v[4];
            #pragma unroll
            for (int q = 0; q < 4; ++q)
                v[q] = h4[(size_t)clampn((int)el[j + q]) * S + lane];
            #pragma unroll
            for (int q = 0; q < 4; ++q) acc16(acc, v[q]);
        }
        for (; j < cap; ++j)
            acc16(acc, h4[(size_t)clampn((int)el[j]) * S + lane]);
        float r = 1.0f / (float)(d > 0 ? d : 1);
        union { unsigned short us[8]; u32x4 u4; } o;
        #pragma unroll
        for (int k = 0; k < 8; ++k) o.us[k] = f2bf(acc[k] * r);
        __builtin_nontemporal_store(o.u4, (u32x4*)agg + (size_t)node * S + lane);
    }
}

// ---------------------------------------------------------------- MFMA GEMMs

// layer 0: out = relu( agg@Wl + h@Wr + b ), split-N: each block does all 128
// rows x one 64-col N-half, staging the contiguous 32KB half of the dual pack.
// 5 blocks/CU LDS-limited -> all 782 blocks co-resident (no 2-round makespan).
__global__ __launch_bounds__(256) void gemm_half(const unsigned short* __restrict__ agg,
                                                 const unsigned short* __restrict__ h,
                                                 const unsigned short* __restrict__ Wpack,
                                                 const float* __restrict__ bias,
                                                 unsigned short* __restrict__ out) {
    __shared__ unsigned short Wlds[128 * 128];    // 32 KB
    int tid = threadIdx.x;
    int nh = blockIdx.x & 1;
    int rb = blockIdx.x >> 1;
    {
        const u32x4* wg = (const u32x4*)Wpack + nh * 2048;
        u32x4* wl = (u32x4*)Wlds;
        #pragma unroll
        for (int i = tid; i < 2048; i += 256) wl[i] = wg[i];
    }
    __syncthreads();

    int wave = tid >> 6, lane = tid & 63;
    int m = lane & 15, quad = lane >> 4;
    int r0 = wave * 16;                           // second tile at r0 + 64
    int row0 = rb * 128 + r0;

    const unsigned short* arow = agg + (size_t)(row0 + m) * 128 + quad * 8;
    const unsigned short* hrow = h   + (size_t)(row0 + m) * 128 + quad * 8;

    f32x4 acc0[4] = {};
    f32x4 acc1[4] = {};
    #pragma unroll
    for (int ks = 0; ks < 8; ++ks) {
        const unsigned short* s = (ks < 4) ? (arow + ks * 32) : (hrow + (ks - 4) * 32);
        bf16x8 a0 = *(const bf16x8*)s;
        bf16x8 a1 = *(const bf16x8*)(s + 64 * 128);
        #pragma unroll
        for (int nt = 0; nt < 4; ++nt) {
            bf16x8 b = *(const bf16x8*)&Wlds[((nt * 8 + ks) * 64 + lane) * 8];
            acc0[nt] = __builtin_amdgcn_mfma_f32_16x16x32_bf16(a0, b, acc0[nt], 0, 0, 0);
            acc1[nt] = __builtin_amdgcn_mfma_f32_16x16x32_bf16(a1, b, acc1[nt], 0, 0, 0);
        }
    }

    #pragma unroll
    for (int t = 0; t < 2; ++t) {
        #pragma unroll
        for (int nt = 0; nt < 4; ++nt) {
            int n = nh * 64 + nt * 16 + m;
            float bv = bias[n];
            #pragma unroll
            for (int r = 0; r < 4; ++r) {
                int row = row0 + t * 64 + quad * 4 + r;   // < NN_PAD; pad rows ok
                float v = fmaxf((t == 0 ? acc0[nt][r] : acc1[nt][r]) + bv, 0.f);
                out[(size_t)row * 128 + n] = f2bf(v);
            }
        }
    }
}

// layer 1: out = relu( agg@Wl + h@Wr + b ), full-N 128-row blocks + fused
// P2 = h2@Wl2 epilogue (needs all 128 h2 cols -> can't split N). Reuses the
// dead 64KB Wlds as the h2 staging tile (barrier-guarded; each wave reads back
// only the rows it wrote -> wave-internal lgkmcnt ordering suffices).
__global__ __launch_bounds__(256) void gemm_dual(const unsigned short* __restrict__ agg,
                                                 const unsigned short* __restrict__ h,
                                                 const unsigned short* __restrict__ Wpack,
                                                 const float* __restrict__ bias,
                                                 unsigned short* __restrict__ out,
                                                 const unsigned short* __restrict__ Wp2,
                                                 unsigned short* __restrict__ P2) {
    __shared__ unsigned short Wlds[128 * 256];    // 64 KB
    int tid = threadIdx.x;
    {
        const u32x4* wg = (const u32x4*)Wpack;
        u32x4* wl = (u32x4*)Wlds;
        #pragma unroll
        for (int i = tid; i < 128 * 32; i += 256) wl[i] = wg[i];
    }
    __syncthreads();

    int wave = tid >> 6, lane = tid & 63;
    int m = lane & 15, quad = lane >> 4;
    int r0 = wave * 16;                           // second tile at r0 + 64
    int row0 = blockIdx.x * 128 + r0;

    const unsigned short* arow = agg + (size_t)(row0 + m) * 128 + quad * 8;
    const unsigned short* hrow = h   + (size_t)(row0 + m) * 128 + quad * 8;

    f32x4 acc0[8] = {};
    f32x4 acc1[8] = {};
    #pragma unroll
    for (int ks = 0; ks < 8; ++ks) {
        const unsigned short* s = (ks < 4) ? (arow + ks * 32) : (hrow + (ks - 4) * 32);
        bf16x8 a0 = *(const bf16x8*)s;
        bf16x8 a1 = *(const bf16x8*)(s + 64 * 128);
        #pragma unroll
        for (int nt = 0; nt < 8; ++nt) {
            bf16x8 b = *(const bf16x8*)&Wlds[((nt * 8 + ks) * 64 + lane) * 8];
            acc0[nt] = __builtin_amdgcn_mfma_f32_16x16x32_bf16(a0, b, acc0[nt], 0, 0, 0);
            acc1[nt] = __builtin_amdgcn_mfma_f32_16x16x32_bf16(a1, b, acc1[nt], 0, 0, 0);
        }
    }

    #pragma unroll
    for (int t = 0; t < 2; ++t) {
        #pragma unroll
        for (int nt = 0; nt < 8; ++nt) {
            int n = nt * 16 + m;
            float bv = bias[n];
            #pragma unroll
            for (int r = 0; r < 4; ++r) {
                int row = row0 + t * 64 + quad * 4 + r;   // < NN_PAD; pad rows ok
                float v = fmaxf((t == 0 ? acc0[nt][r] : acc1[nt][r]) + bv, 0.f);
                out[(size_t)row * 128 + n] = f2bf(v);
            }
        }
    }

    {
        constexpr int RS = 136;                   // padded row stride (shorts)
        __syncthreads();                          // Wlds reads done by all waves
        #pragma unroll
        for (int t = 0; t < 2; ++t) {
            #pragma unroll
            for (int nt = 0; nt < 8; ++nt) {
                int n = nt * 16 + m;
                float bv = bias[n];
                #pragma unroll
                for (int r = 0; r < 4; ++r) {
                    int rl = t * 64 + r0 + quad * 4 + r;
                    float v = fmaxf((t == 0 ? acc0[nt][r] : acc1[nt][r]) + bv, 0.f);
                    Wlds[rl * RS + n] = f2bf(v);
                }
            }
        }
        f32x4 p0[4] = {};
        f32x4 p1[4] = {};
        #pragma unroll
        for (int ks = 0; ks < 4; ++ks) {
            bf16x8 a0 = *(const bf16x8*)&Wlds[(r0 + m) * RS + ks * 32 + quad * 8];
            bf16x8 a1 = *(const bf16x8*)&Wlds[(64 + r0 + m) * RS + ks * 32 + quad * 8];
            #pragma unroll
            for (int nt = 0; nt < 4; ++nt) {
                bf16x8 bfr = *(const bf16x8*)&Wp2[((size_t)(nt * 4 + ks) * 64 + lane) * 8];
                p0[nt] = __builtin_amdgcn_mfma_f32_16x16x32_bf16(a0, bfr, p0[nt], 0, 0, 0);
                p1[nt] = __builtin_amdgcn_mfma_f32_16x16x32_bf16(a1, bfr, p1[nt], 0, 0, 0);
            }
        }
        #pragma unroll
        for (int t = 0; t < 2; ++t) {
            #pragma unroll
            for (int nt = 0; nt < 4; ++nt) {
                int n = nt * 16 + m;
                #pragma unroll
                for (int r = 0; r < 4; ++r) {
                    int rl = t * 64 + r0 + quad * 4 + r;
                    P2[(size_t)(blockIdx.x * 128 + rl) * 64 + n] =
                        f2bf(t == 0 ? p0[nt][r] : p1[nt][r]);
                }
            }
        }
    }
}

// out = h @ Wr2 + aggP + bias (K=128, N=64), fp32 out — layer-2 final.
// 64-row tiles (782 blocks), 16KB W stage -> fully co-resident & balanced.
__global__ __launch_bounds__(256) void gemm_final(const unsigned short* __restrict__ h,
                                                  const unsigned short* __restrict__ Wpack,
                                                  const float* __restrict__ bias,
                                                  const unsigned short* __restrict__ aggP,
                                                  float* __restrict__ outp) {
    __shared__ unsigned short Wlds[64 * 128];     // 16 KB
    int tid = threadIdx.x;
    {
        const u32x4* wg = (const u32x4*)Wpack;
        u32x4* wl = (u32x4*)Wlds;
        #pragma unroll
        for (int i = tid; i < 1024; i += 256) wl[i] = wg[i];
    }
    __syncthreads();

    int wave = tid >> 6, lane = tid & 63;
    int m = lane & 15, quad = lane >> 4;
    int row0 = blockIdx.x * 64 + wave * 16;

    const unsigned short* hrow = h + (size_t)(row0 + m) * 128 + quad * 8;

    f32x4 acc0[4] = {};
    #pragma unroll
    for (int ks = 0; ks < 4; ++ks) {
        bf16x8 a0 = *(const bf16x8*)(hrow + ks * 32);
        #pragma unroll
        for (int nt = 0; nt < 4; ++nt) {
            bf16x8 b = *(const bf16x8*)&Wlds[((nt * 4 + ks) * 64 + lane) * 8];
            acc0[nt] = __builtin_amdgcn_mfma_f32_16x16x32_bf16(a0, b, acc0[nt], 0, 0, 0);
        }
    }

    #pragma unroll
    for (int nt = 0; nt < 4; ++nt) {
        int n = nt * 16 + m;
        float bv = bias[n];
        #pragma unroll
        for (int r = 0; r < 4; ++r) {
            int row = row0 + quad * 4 + r;
            if (row < NN) {
                float av = bflo2f((unsigned)aggP[(size_t)row * 64 + n]);
                outp[(size_t)row * 64 + n] = acc0[nt][r] + bv + av;
            }
        }
    }
}

// ---------------------------------------------------------------- launch

static inline size_t align256(size_t x) { return (x + 255) & ~(size_t)255; }

extern "C" void kernel_launch(void* const* d_in, const int* in_sizes, int n_in,
                              void* d_out, int out_size, void* d_ws, size_t ws_size,
                              hipStream_t stream) {
    const float* x    = (const float*)d_in[0];
    const int*   ei   = (const int*)d_in[1];
    const int*   esrc = ei;
    const int*   edst = ei + NE;
    const float* Wl0 = (const float*)d_in[2];
    const float* bl0 = (const float*)d_in[3];
    const float* Wr0 = (const float*)d_in[4];
    const float* Wl1 = (const float*)d_in[5];
    const float* bl1 = (const float*)d_in[6];
    const float* Wr1 = (const float*)d_in[7];
    const float* Wl2 = (const float*)d_in[8];
    const float* bl2 = (const float*)d_in[9];
    const float* Wr2 = (const float*)d_in[10];

    char* ws = (char*)d_ws;
    size_t off = 0;
    int* gcount = (int*)(ws + off);             off = align256(off + (size_t)NBKT * 4);
    unsigned* bucketbuf = (unsigned*)(ws + off);
    off = align256(off + (size_t)NBKT * BKTCAP * 4);
    unsigned short* eidx2 = (unsigned short*)(ws + off);
    off = align256(off + (size_t)NN * CAP2 * 2);
    int* deg = (int*)(ws + off);                off = align256(off + (size_t)NN * 4);
    unsigned short* xb   = (unsigned short*)(ws + off); off = align256(off + (size_t)NN_PAD * DK * 2);
    unsigned short* bAgg = (unsigned short*)(ws + off); off = align256(off + (size_t)NN_PAD * DK * 2);
    unsigned short* bH   = (unsigned short*)(ws + off); off = align256(off + (size_t)NN_PAD * DK * 2);
    unsigned short* P2   = (unsigned short*)(ws + off); off = align256(off + (size_t)NN_PAD * 64 * 2);
    unsigned short* aggP = (unsigned short*)(ws + off); off = align256(off + (size_t)NN_PAD * 64 * 2);
    unsigned short* Wp0  = (unsigned short*)(ws + off); off = align256(off + (size_t)256 * 128 * 2);
    unsigned short* Wp1  = (unsigned short*)(ws + off); off = align256(off + (size_t)256 * 128 * 2);
    unsigned short* Wp2l = (unsigned short*)(ws + off); off = align256(off + (size_t)128 * 64 * 2);
    unsigned short* Wp2r = (unsigned short*)(ws + off); off = align256(off + (size_t)128 * 64 * 2);

    // ---- setup: convert + packs + gcount zero, then adjacency build ----
    prep<<<NN_PAD * DK / 8 / 256 + 32 + 8 + 1, 256, 0, stream>>>(
        x, xb, Wl0, Wr0, Wp0, Wl1, Wr1, Wp1, Wl2, Wp2l, Wr2, Wp2r, gcount);
    partition_edges<<<(NE / 8 + 255) / 256, 256, 0, stream>>>(esrc, edst, gcount, bucketbuf);
    build_lists<<<NBKT, 256, 0, stream>>>(gcount, bucketbuf, eidx2, deg);

    // ---- layer 0: xb -> bH (relu), split-N GEMM ----
    aggregate<16><<<AGG_BLOCKS, 256, 0, stream>>>(xb, eidx2, deg, bAgg);
    gemm_half<<<GRID_HALF, 256, 0, stream>>>(bAgg, xb, Wp0, bl0, bH);

    // ---- layer 1 (+ fused P2 = h2@Wl2): bH -> xb, P2 ----
    aggregate<16><<<AGG_BLOCKS, 256, 0, stream>>>(bH, eidx2, deg, bAgg);
    gemm_dual<<<GRID_DUAL, 256, 0, stream>>>(bAgg, bH, Wp1, bl1, xb, Wp2l, P2);

    // ---- layer 2: out = xb@Wr2 + agg(P2) + bias ----
    aggregate<8><<<AGG_BLOCKS, 256, 0, stream>>>(P2, eidx2, deg, aggP);
    gemm_final<<<GRID_FIN, 256, 0, stream>>>(xb, Wp2r, bl2, aggP, (float*)d_out);
}

// Round 8
// 222.105 us; speedup vs baseline: 1.1107x; 1.0881x over previous
//
#include <hip/hip_runtime.h>

#define NN 50000
#define NE 800000
#define DK 128            // feature dim into layers 0/1
#define NN_PAD 50048      // multiple of 128 for GEMM row blocks

// window-ordered dense adjacency lists
#define SW 7              // src windows (src >> 13)
#define SUBCAP 20         // per-window cap (never hit at mean deg 16/7)
#define CAP2 64           // total per-node cap (never hit at mean deg 16)

// two-phase edge partition: bucket = dst >> 7 (128 nodes/bucket)
#define NPB 128
#define NBKT 391          // ceil(50000/128)
#define BKTCAP 4096       // avg 2048/bucket, Poisson std ~45 -> hugely safe

#define GRID_DUAL 391     // NN_PAD/128 — layer-1 GEMM (full-N, P2+F epilogue)
#define GRID_HALF 782     // layer-0 GEMM: 128 rows x 64-col N-half per block

// aggregate: one node per 16-lane group, 8-deep gather unroll — the measured
// local optimum (R6 depth-4: +16us; R7 depth-16: +11us; R5 depth-8: best).
// MUST stay a separate wide-grid kernel (R2 lesson: fusing into the GEMM grid
// dropped gather occupancy 24->6 waves/CU, fetch 15->80MB).
// W must stay LDS-staged per block in GEMMs (R4 lesson).
#define AGG_BLOCKS 1568

typedef __attribute__((ext_vector_type(8))) short bf16x8;
typedef __attribute__((ext_vector_type(4))) float f32x4;
typedef __attribute__((ext_vector_type(2))) int   i32x2;
typedef __attribute__((ext_vector_type(4))) int   i32x4;
typedef __attribute__((ext_vector_type(4))) unsigned u32x4;
typedef __attribute__((ext_vector_type(8))) unsigned short u16x8;

__device__ inline unsigned short f2bf(float f) {
    unsigned u = __builtin_bit_cast(unsigned, f);
    u = (u + 0x7FFFu + ((u >> 16) & 1u)) >> 16;
    return (unsigned short)u;
}
__device__ inline float bfhi2f(unsigned u) {
    return __builtin_bit_cast(float, u & 0xFFFF0000u);
}
__device__ inline float bflo2f(unsigned u) {
    return __builtin_bit_cast(float, u << 16);
}
__device__ inline int clampn(int v) {           // ushort ids >= 0 already
    return v >= NN ? NN - 1 : v;
}
__device__ inline void acc16(float* acc, u32x4 v) {
    acc[0] += bflo2f(v.x); acc[1] += bfhi2f(v.x);
    acc[2] += bflo2f(v.y); acc[3] += bfhi2f(v.y);
    acc[4] += bflo2f(v.z); acc[5] += bfhi2f(v.z);
    acc[6] += bflo2f(v.w); acc[7] += bfhi2f(v.w);
}

// ---------------------------------------------------------------- adjacency build

// Phase 1: partition edges into dst-buckets. All global writes are
// per-bucket streams (runs of consecutive u32s), keeping the 6.4MB
// bucket buffer L2/L3-resident — no random 64B-line HBM writebacks.
__global__ __launch_bounds__(256) void partition_edges(const int* __restrict__ src,
                                                       const int* __restrict__ dst,
                                                       int* __restrict__ gcount,
                                                       unsigned* __restrict__ bucketbuf) {
    __shared__ int hist[NBKT];
    __shared__ int cur[NBKT];
    __shared__ int base[NBKT];
    int tid = threadIdx.x;
    for (int i = tid; i < NBKT; i += 256) { hist[i] = 0; cur[i] = 0; }
    __syncthreads();

    unsigned rec[8];
    int bkt[8];
    int e0 = (blockIdx.x * 256 + tid) * 8;       // NE % 8 == 0
    bool valid = e0 < NE;
    if (valid) {
        i32x4 sa = __builtin_nontemporal_load((const i32x4*)(src + e0));
        i32x4 sb = __builtin_nontemporal_load((const i32x4*)(src + e0 + 4));
        i32x4 da = __builtin_nontemporal_load((const i32x4*)(dst + e0));
        i32x4 db = __builtin_nontemporal_load((const i32x4*)(dst + e0 + 4));
        int ss[8] = {sa.x, sa.y, sa.z, sa.w, sb.x, sb.y, sb.z, sb.w};
        int dd[8] = {da.x, da.y, da.z, da.w, db.x, db.y, db.z, db.w};
        #pragma unroll
        for (int k = 0; k < 8; ++k) {
            bkt[k] = dd[k] >> 7;
            rec[k] = (unsigned)ss[k] | ((unsigned)(dd[k] & 127) << 16);
            atomicAdd(&hist[bkt[k]], 1);
        }
    }
    __syncthreads();
    for (int i = tid; i < NBKT; i += 256)
        base[i] = atomicAdd(&gcount[i], hist[i]);
    __syncthreads();
    if (valid) {
        #pragma unroll
        for (int k = 0; k < 8; ++k) {
            int pos = base[bkt[k]] + atomicAdd(&cur[bkt[k]], 1);
            if (pos < BKTCAP)
                bucketbuf[(size_t)bkt[k] * BKTCAP + pos] = rec[k];
        }
    }
}

// Phase 2: one block per bucket. Windowed histogram + slotting entirely in
// LDS; dense window-ordered eidx2 rows + deg written out coalesced.
__global__ __launch_bounds__(256) void build_lists(const int* __restrict__ gcount,
                                                   const unsigned* __restrict__ bucketbuf,
                                                   unsigned short* __restrict__ eidx2,
                                                   int* __restrict__ deg) {
    __shared__ unsigned short list[NPB * CAP2];   // 16 KB
    __shared__ int cnt[NPB * 8];                  // 4 KB
    __shared__ int cur[NPB * 8];                  // 4 KB
    __shared__ int off_[NPB * 8];                 // 4 KB
    int b = blockIdx.x, tid = threadIdx.x;
    int n0 = b << 7;
    int cntE = gcount[b];
    if (cntE > BKTCAP) cntE = BKTCAP;

    for (int i = tid; i < NPB * 8; i += 256) { cnt[i] = 0; cur[i] = 0; }
    u32x4* l4 = (u32x4*)list;
    for (int i = tid; i < NPB * CAP2 / 8; i += 256)
        l4[i] = (u32x4){0u, 0u, 0u, 0u};
    __syncthreads();

    const unsigned* bb = bucketbuf + (size_t)b * BKTCAP;
    for (int i = tid; i < cntE; i += 256) {
        unsigned r = bb[i];
        int nl = r >> 16;
        int w  = (r & 0xFFFFu) >> 13;
        atomicAdd(&cnt[nl * 8 + w], 1);
    }
    __syncthreads();

    if (tid < NPB) {
        int run = 0, dt = 0;
        #pragma unroll
        for (int w = 0; w < SW; ++w) {
            int c = cnt[tid * 8 + w];
            dt += c;
            off_[tid * 8 + w] = run;
            run += (c < SUBCAP) ? c : SUBCAP;
        }
        if (n0 + tid < NN) deg[n0 + tid] = dt;    // uncapped true degree
    }
    __syncthreads();

    for (int i = tid; i < cntE; i += 256) {
        unsigned r = bb[i];
        int s  = (int)(r & 0xFFFFu);
        int nl = r >> 16;
        int w  = s >> 13;
        int slot = atomicAdd(&cur[nl * 8 + w], 1);
        int pos  = off_[nl * 8 + w] + slot;
        if (slot < SUBCAP && pos < CAP2)
            list[nl * CAP2 + pos] = (unsigned short)s;
    }
    __syncthreads();

    int nvalid = NN - n0;
    if (nvalid > NPB) nvalid = NPB;
    u32x4* out4 = (u32x4*)(eidx2 + (size_t)n0 * CAP2);
    for (int i = tid; i < nvalid * (CAP2 / 8); i += 256)
        __builtin_nontemporal_store(l4[i], out4 + i);
}

// ---------------------------------------------------------------- prep (fused setup)
// blocks [0,3128): x -> bf16 (+ zero NN..NN_PAD pad rows)
// next 32: dual W packs (16 for layer0, 16 for layer1)
// next 8:  single W packs (4 Wl2, 4 Wr2)
// last 1:  zero gcount
__global__ __launch_bounds__(256) void prep(const float* __restrict__ x,
                                            unsigned short* __restrict__ xb,
                                            const float* __restrict__ Wl0,
                                            const float* __restrict__ Wr0,
                                            unsigned short* __restrict__ Wp0,
                                            const float* __restrict__ Wl1,
                                            const float* __restrict__ Wr1,
                                            unsigned short* __restrict__ Wp1,
                                            const float* __restrict__ Wl2,
                                            unsigned short* __restrict__ Wp2l,
                                            const float* __restrict__ Wr2,
                                            unsigned short* __restrict__ Wp2r,
                                            int* __restrict__ gcount) {
    int b = blockIdx.x;
    if (b < NN_PAD * DK / 8 / 256) {                       // 3128 convert blocks
        long long i = ((long long)b * 256 + threadIdx.x) * 8;
        if (i < (long long)NN * DK) {
            f32x4 a = __builtin_nontemporal_load((const f32x4*)(x + i));
            f32x4 c = __builtin_nontemporal_load((const f32x4*)(x + i + 4));
            union { unsigned short us[8]; u32x4 u4; } o;
            o.us[0] = f2bf(a.x); o.us[1] = f2bf(a.y); o.us[2] = f2bf(a.z); o.us[3] = f2bf(a.w);
            o.us[4] = f2bf(c.x); o.us[5] = f2bf(c.y); o.us[6] = f2bf(c.z); o.us[7] = f2bf(c.w);
            *(u32x4*)(xb + i) = o.u4;
        } else {
            *(u32x4*)(xb + i) = (u32x4){0u, 0u, 0u, 0u};   // pad rows -> 0
        }
        return;
    }
    b -= NN_PAD * DK / 8 / 256;
    if (b < 32) {                                          // dual 256x128 packs
        const float* Wl = (b < 16) ? Wl0 : Wl1;
        const float* Wr = (b < 16) ? Wr0 : Wr1;
        unsigned short* Wp = (b < 16) ? Wp0 : Wp1;
        int tid = (b & 15) * 256 + threadIdx.x;            // 0..4095
        int l  = tid & 63;
        int ks = (tid >> 6) & 7;
        int nt = tid >> 9;
        int n  = nt * 16 + (l & 15);
        int kb = ks * 32 + (l >> 4) * 8;
        union { unsigned short us[8]; u32x4 u4; } o;
        #pragma unroll
        for (int j = 0; j < 8; ++j) {
            int k = kb + j;
            float w = (k < 128) ? Wl[k * 128 + n] : Wr[(k - 128) * 128 + n];
            o.us[j] = f2bf(w);
        }
        *(u32x4*)(Wp + (size_t)tid * 8) = o.u4;
        return;
    }
    b -= 32;
    if (b < 8) {                                           // single 128x64 packs
        const float* W = (b < 4) ? Wl2 : Wr2;
        unsigned short* Wp = (b < 4) ? Wp2l : Wp2r;
        int tid = (b & 3) * 256 + threadIdx.x;             // 0..1023
        int l  = tid & 63;
        int ks = (tid >> 6) & 3;
        int nt = tid >> 8;
        int n  = nt * 16 + (l & 15);
        int kb = ks * 32 + (l >> 4) * 8;
        union { unsigned short us[8]; u32x4 u4; } o;
        #pragma unroll
        for (int j = 0; j < 8; ++j) o.us[j] = f2bf(W[(kb + j) * 64 + n]);
        *(u32x4*)(Wp + (size_t)tid * 8) = o.u4;
        return;
    }
    for (int i = threadIdx.x; i < NBKT; i += 256) gcount[i] = 0;
}

// ---------------------------------------------------------------- aggregation (bf16)
// R5 form: one node per S-lane group, 8-deep gather unroll (measured optimum).
// FIN (layer 2): fused final — out = F + mean(gathered P2); F = h2@Wr2 + bl2
// precomputed by gemm_dual. Removes the gemm_final dispatch + aggP round-trip.
// S = 16B-chunks per feature row (16 -> 128 dims, 8 -> 64 dims).
template <int S, bool FIN>
__global__ __launch_bounds__(256) void aggregate(const unsigned short* __restrict__ h,
                                                 const unsigned short* __restrict__ eidx2,
                                                 const int* __restrict__ deg,
                                                 unsigned short* __restrict__ agg,
                                                 const float* __restrict__ F,
                                                 float* __restrict__ outp) {
    constexpr int NPB_ = 256 / S;         // nodes per block
    int g    = threadIdx.x / S;
    int lane = threadIdx.x % S;
    const u32x4* h4 = (const u32x4*)h;
    for (int base = 0; base < NN; base += AGG_BLOCKS * NPB_) {
        int node = base + blockIdx.x * NPB_ + g;
        if (node >= NN) continue;
        int d   = deg[node];
        int cap = (d < CAP2) ? d : CAP2;
        const unsigned short* el = eidx2 + (size_t)node * CAP2;  // 128B aligned
        float acc[8] = {0.f, 0.f, 0.f, 0.f, 0.f, 0.f, 0.f, 0.f};
        int j = 0;
        for (; j + 7 < cap; j += 8) {
            u16x8 i8 = *(const u16x8*)(el + j);      // 16B aligned (j%8==0)
            u32x4 v[8];
            #pragma unroll
            for (int q = 0; q < 8; ++q)
                v[q] = h4[(size_t)clampn((int)i8[q]) * S + lane];
            #pragma unroll
            for (int q = 0; q < 8; ++q) acc16(acc, v[q]);
        }
        for (; j + 3 < cap; j += 4) {
            u32x4 v[4];
            #pragma unroll
            for (int q = 0; q < 4; ++q)
                v[q] = h4[(size_t)clampn((int)el[j + q]) * S + lane];
            #pragma unroll
            for (int q = 0; q < 4; ++q) acc16(acc, v[q]);
        }
        for (; j < cap; ++j)
            acc16(acc, h4[(size_t)clampn((int)el[j]) * S + lane]);
        float r = 1.0f / (float)(d > 0 ? d : 1);
        if constexpr (FIN) {
            const float* fr = F + (size_t)node * 64 + lane * 8;
            f32x4 f0 = *(const f32x4*)fr;
            f32x4 f1 = *(const f32x4*)(fr + 4);
            f32x4 o0, o1;
            o0.x = f0.x + acc[0] * r; o0.y = f0.y + acc[1] * r;
            o0.z = f0.z + acc[2] * r; o0.w = f0.w + acc[3] * r;
            o1.x = f1.x + acc[4] * r; o1.y = f1.y + acc[5] * r;
            o1.z = f1.z + acc[6] * r; o1.w = f1.w + acc[7] * r;
            float* op = outp + (size_t)node * 64 + lane * 8;
            __builtin_nontemporal_store(o0, (f32x4*)op);
            __builtin_nontemporal_store(o1, (f32x4*)(op + 4));
        } else {
            union { unsigned short us[8]; u32x4 u4; } o;
            #pragma unroll
            for (int k = 0; k < 8; ++k) o.us[k] = f2bf(acc[k] * r);
            __builtin_nontemporal_store(o.u4, (u32x4*)agg + (size_t)node * S + lane);
        }
    }
}

// ---------------------------------------------------------------- MFMA GEMMs

// layer 0: out = relu( agg@Wl + h@Wr + b ), split-N: each block does all 128
// rows x one 64-col N-half, staging the contiguous 32KB half of the dual pack.
// 5 blocks/CU LDS-limited -> all 782 blocks co-resident (no 2-round makespan).
__global__ __launch_bounds__(256) void gemm_half(const unsigned short* __restrict__ agg,
                                                 const unsigned short* __restrict__ h,
                                                 const unsigned short* __restrict__ Wpack,
                                                 const float* __restrict__ bias,
                                                 unsigned short* __restrict__ out) {
    __shared__ unsigned short Wlds[128 * 128];    // 32 KB
    int tid = threadIdx.x;
    int nh = blockIdx.x & 1;
    int rb = blockIdx.x >> 1;
    {
        const u32x4* wg = (const u32x4*)Wpack + nh * 2048;
        u32x4* wl = (u32x4*)Wlds;
        #pragma unroll
        for (int i = tid; i < 2048; i += 256) wl[i] = wg[i];
    }
    __syncthreads();

    int wave = tid >> 6, lane = tid & 63;
    int m = lane & 15, quad = lane >> 4;
    int r0 = wave * 16;                           // second tile at r0 + 64
    int row0 = rb * 128 + r0;

    const unsigned short* arow = agg + (size_t)(row0 + m) * 128 + quad * 8;
    const unsigned short* hrow = h   + (size_t)(row0 + m) * 128 + quad * 8;

    f32x4 acc0[4] = {};
    f32x4 acc1[4] = {};
    #pragma unroll
    for (int ks = 0; ks < 8; ++ks) {
        const unsigned short* s = (ks < 4) ? (arow + ks * 32) : (hrow + (ks - 4) * 32);
        bf16x8 a0 = *(const bf16x8*)s;
        bf16x8 a1 = *(const bf16x8*)(s + 64 * 128);
        #pragma unroll
        for (int nt = 0; nt < 4; ++nt) {
            bf16x8 b = *(const bf16x8*)&Wlds[((nt * 8 + ks) * 64 + lane) * 8];
            acc0[nt] = __builtin_amdgcn_mfma_f32_16x16x32_bf16(a0, b, acc0[nt], 0, 0, 0);
            acc1[nt] = __builtin_amdgcn_mfma_f32_16x16x32_bf16(a1, b, acc1[nt], 0, 0, 0);
        }
    }

    #pragma unroll
    for (int t = 0; t < 2; ++t) {
        #pragma unroll
        for (int nt = 0; nt < 4; ++nt) {
            int n = nh * 64 + nt * 16 + m;
            float bv = bias[n];
            #pragma unroll
            for (int r = 0; r < 4; ++r) {
                int row = row0 + t * 64 + quad * 4 + r;   // < NN_PAD; pad rows ok
                float v = fmaxf((t == 0 ? acc0[nt][r] : acc1[nt][r]) + bv, 0.f);
                out[(size_t)row * 128 + n] = f2bf(v);
            }
        }
    }
}

// layer 1: out = relu( agg@Wl + h@Wr + b ), full-N 128-row blocks + fused
// epilogue computing BOTH P2 = h2@Wl2 (bf16) and F = h2@Wr2 + bl2 (fp32) from
// the same LDS h2 tile (Wlds reused dead after main GEMM; barrier-guarded;
// each wave reads back only rows it wrote -> wave-internal lgkmcnt suffices).
// F lets aggregate<8,FIN> produce the final output without a gemm_final pass.
__global__ __launch_bounds__(256) void gemm_dual(const unsigned short* __restrict__ agg,
                                                 const unsigned short* __restrict__ h,
                                                 const unsigned short* __restrict__ Wpack,
                                                 const float* __restrict__ bias,
                                                 unsigned short* __restrict__ out,
                                                 const unsigned short* __restrict__ Wp2l,
                                                 const unsigned short* __restrict__ Wp2r,
                                                 const float* __restrict__ bias2,
                                                 unsigned short* __restrict__ P2,
                                                 float* __restrict__ Fout) {
    __shared__ unsigned short Wlds[128 * 256];    // 64 KB
    int tid = threadIdx.x;
    {
        const u32x4* wg = (const u32x4*)Wpack;
        u32x4* wl = (u32x4*)Wlds;
        #pragma unroll
        for (int i = tid; i < 128 * 32; i += 256) wl[i] = wg[i];
    }
    __syncthreads();

    int wave = tid >> 6, lane = tid & 63;
    int m = lane & 15, quad = lane >> 4;
    int r0 = wave * 16;                           // second tile at r0 + 64
    int row0 = blockIdx.x * 128 + r0;

    const unsigned short* arow = agg + (size_t)(row0 + m) * 128 + quad * 8;
    const unsigned short* hrow = h   + (size_t)(row0 + m) * 128 + quad * 8;

    f32x4 acc0[8] = {};
    f32x4 acc1[8] = {};
    #pragma unroll
    for (int ks = 0; ks < 8; ++ks) {
        const unsigned short* s = (ks < 4) ? (arow + ks * 32) : (hrow + (ks - 4) * 32);
        bf16x8 a0 = *(const bf16x8*)s;
        bf16x8 a1 = *(const bf16x8*)(s + 64 * 128);
        #pragma unroll
        for (int nt = 0; nt < 8; ++nt) {
            bf16x8 b = *(const bf16x8*)&Wlds[((nt * 8 + ks) * 64 + lane) * 8];
            acc0[nt] = __builtin_amdgcn_mfma_f32_16x16x32_bf16(a0, b, acc0[nt], 0, 0, 0);
            acc1[nt] = __builtin_amdgcn_mfma_f32_16x16x32_bf16(a1, b, acc1[nt], 0, 0, 0);
        }
    }

    #pragma unroll
    for (int t = 0; t < 2; ++t) {
        #pragma unroll
        for (int nt = 0; nt < 8; ++nt) {
            int n = nt * 16 + m;
            float bv = bias[n];
            #pragma unroll
            for (int r = 0; r < 4; ++r) {
                int row = row0 + t * 64 + quad * 4 + r;   // < NN_PAD; pad rows ok
                float v = fmaxf((t == 0 ? acc0[nt][r] : acc1[nt][r]) + bv, 0.f);
                out[(size_t)row * 128 + n] = f2bf(v);
            }
        }
    }

    {
        constexpr int RS = 136;                   // padded row stride (shorts)
        __syncthreads();                          // Wlds reads done by all waves
        #pragma unroll
        for (int t = 0; t < 2; ++t) {
            #pragma unroll
            for (int nt = 0; nt < 8; ++nt) {
                int n = nt * 16 + m;
                float bv = bias[n];
                #pragma unroll
                for (int r = 0; r < 4; ++r) {
                    int rl = t * 64 + r0 + quad * 4 + r;
                    float v = fmaxf((t == 0 ? acc0[nt][r] : acc1[nt][r]) + bv, 0.f);
                    Wlds[rl * RS + n] = f2bf(v);
                }
            }
        }
        f32x4 p0[4] = {};
        f32x4 p1[4] = {};
        f32x4 q0[4] = {};
        f32x4 q1[4] = {};
        #pragma unroll
        for (int ks = 0; ks < 4; ++ks) {
            bf16x8 a0 = *(const bf16x8*)&Wlds[(r0 + m) * RS + ks * 32 + quad * 8];
            bf16x8 a1 = *(const bf16x8*)&Wlds[(64 + r0 + m) * RS + ks * 32 + quad * 8];
            #pragma unroll
            for (int nt = 0; nt < 4; ++nt) {
                bf16x8 bl = *(const bf16x8*)&Wp2l[((size_t)(nt * 4 + ks) * 64 + lane) * 8];
                bf16x8 br = *(const bf16x8*)&Wp2r[((size_t)(nt * 4 + ks) * 64 + lane) * 8];
                p0[nt] = __builtin_amdgcn_mfma_f32_16x16x32_bf16(a0, bl, p0[nt], 0, 0, 0);
                p1[nt] = __builtin_amdgcn_mfma_f32_16x16x32_bf16(a1, bl, p1[nt], 0, 0, 0);
                q0[nt] = __builtin_amdgcn_mfma_f32_16x16x32_bf16(a0, br, q0[nt], 0, 0, 0);
                q1[nt] = __builtin_amdgcn_mfma_f32_16x16x32_bf16(a1, br, q1[nt], 0, 0, 0);
            }
        }
        #pragma unroll
        for (int t = 0; t < 2; ++t) {
            #pragma unroll
            for (int nt = 0; nt < 4; ++nt) {
                int n = nt * 16 + m;
                float b2 = bias2[n];
                #pragma unroll
                for (int r = 0; r < 4; ++r) {
                    int rl = t * 64 + r0 + quad * 4 + r;
                    size_t row = (size_t)(blockIdx.x * 128 + rl);
                    P2[row * 64 + n]   = f2bf(t == 0 ? p0[nt][r] : p1[nt][r]);
                    Fout[row * 64 + n] = (t == 0 ? q0[nt][r] : q1[nt][r]) + b2;
                }
            }
        }
    }
}

// ---------------------------------------------------------------- launch

static inline size_t align256(size_t x) { return (x + 255) & ~(size_t)255; }

extern "C" void kernel_launch(void* const* d_in, const int* in_sizes, int n_in,
                              void* d_out, int out_size, void* d_ws, size_t ws_size,
                              hipStream_t stream) {
    const float* x    = (const float*)d_in[0];
    const int*   ei   = (const int*)d_in[1];
    const int*   esrc = ei;
    const int*   edst = ei + NE;
    const float* Wl0 = (const float*)d_in[2];
    const float* bl0 = (const float*)d_in[3];
    const float* Wr0 = (const float*)d_in[4];
    const float* Wl1 = (const float*)d_in[5];
    const float* bl1 = (const float*)d_in[6];
    const float* Wr1 = (const float*)d_in[7];
    const float* Wl2 = (const float*)d_in[8];
    const float* bl2 = (const float*)d_in[9];
    const float* Wr2 = (const float*)d_in[10];

    char* ws = (char*)d_ws;
    size_t off = 0;
    int* gcount = (int*)(ws + off);             off = align256(off + (size_t)NBKT * 4);
    unsigned* bucketbuf = (unsigned*)(ws + off);
    off = align256(off + (size_t)NBKT * BKTCAP * 4);
    unsigned short* eidx2 = (unsigned short*)(ws + off);
    off = align256(off + (size_t)NN * CAP2 * 2);
    int* deg = (int*)(ws + off);                off = align256(off + (size_t)NN * 4);
    unsigned short* xb   = (unsigned short*)(ws + off); off = align256(off + (size_t)NN_PAD * DK * 2);
    unsigned short* bAgg = (unsigned short*)(ws + off); off = align256(off + (size_t)NN_PAD * DK * 2);
    unsigned short* bH   = (unsigned short*)(ws + off); off = align256(off + (size_t)NN_PAD * DK * 2);
    unsigned short* P2   = (unsigned short*)(ws + off); off = align256(off + (size_t)NN_PAD * 64 * 2);
    float*          Fbuf = (float*)(ws + off);          off = align256(off + (size_t)NN_PAD * 64 * 4);
    unsigned short* Wp0  = (unsigned short*)(ws + off); off = align256(off + (size_t)256 * 128 * 2);
    unsigned short* Wp1  = (unsigned short*)(ws + off); off = align256(off + (size_t)256 * 128 * 2);
    unsigned short* Wp2l = (unsigned short*)(ws + off); off = align256(off + (size_t)128 * 64 * 2);
    unsigned short* Wp2r = (unsigned short*)(ws + off); off = align256(off + (size_t)128 * 64 * 2);

    // ---- setup: convert + packs + gcount zero, then adjacency build ----
    prep<<<NN_PAD * DK / 8 / 256 + 32 + 8 + 1, 256, 0, stream>>>(
        x, xb, Wl0, Wr0, Wp0, Wl1, Wr1, Wp1, Wl2, Wp2l, Wr2, Wp2r, gcount);
    partition_edges<<<(NE / 8 + 255) / 256, 256, 0, stream>>>(esrc, edst, gcount, bucketbuf);
    build_lists<<<NBKT, 256, 0, stream>>>(gcount, bucketbuf, eidx2, deg);

    // ---- layer 0: xb -> bH (relu), split-N GEMM ----
    aggregate<16, false><<<AGG_BLOCKS, 256, 0, stream>>>(xb, eidx2, deg, bAgg,
                                                         nullptr, nullptr);
    gemm_half<<<GRID_HALF, 256, 0, stream>>>(bAgg, xb, Wp0, bl0, bH);

    // ---- layer 1: bH -> xb; epilogue: P2 = h2@Wl2, F = h2@Wr2 + bl2 ----
    aggregate<16, false><<<AGG_BLOCKS, 256, 0, stream>>>(bH, eidx2, deg, bAgg,
                                                         nullptr, nullptr);
    gemm_dual<<<GRID_DUAL, 256, 0, stream>>>(bAgg, bH, Wp1, bl1, xb,
                                             Wp2l, Wp2r, bl2, P2, Fbuf);

    // ---- layer 2 (fused final): out = F + mean(gather(P2)) ----
    aggregate<8, true><<<AGG_BLOCKS, 256, 0, stream>>>(P2, eidx2, deg, nullptr,
                                                       Fbuf, (float*)d_out);
}